// Round 9
// baseline (9620.399 us; speedup 1.0000x reference)
//
#include <hip/hip_runtime.h>
#include <hip/hip_bf16.h>
#include <stdint.h>
#include <cstdio>
#include <math.h>

// ---------------------------------------------------------------------------
// SpikingTradingAgent on MI355X — round 9.
// Numerics FROZEN (rounds 4-8 passed, absmax 1.07e-2): f32-faithful
// sequential-i einsum chain, f32 membrane update in reference op order,
// -0.0 refractory encoding, CR-exp sigmoid encoder, ballot spike bits.
//
// Round-9 change (scheduling only, bit-identical arithmetic):
// r8 hit VALUBusy 93% but ~3.1 cy/VALU-instr effective. Hypothesis H1: the
// inner loop carries fat (byte extracts, cvts, movs, 64-bit addr). This round
// deletes ALL of it via v_fma_mix_f32: spikes stored as f16 {0,1} (exact);
// one instruction does f16->f32 convert + f32 fma (single rounding) ==
// fl(sp*w + acc) == the frozen chain. Inner loop: 64 fma_mix + 1 spike
// dwordx4 + 2 uniform W float4 + ~3 addr. f16 spike buffer = 128MB -> 208MB
// workspace layout (overlays encT/hid); r8 u8 path kept as fallback if
// ws_size < 208MB (deterministic dispatch on ws_size).
// ---------------------------------------------------------------------------

typedef unsigned int u32;
typedef unsigned long long u64;

// ---- small (r8, 160MB) layout ----
#define S_ENCT 0u
#define S_BITS (8u << 20)
#define S_WT   (16u << 20)
#define S_SPF  (24u << 20)
#define S_CB   (88u << 20)
#define S_HID  (152u << 20)
#define WS_SMALL ((size_t)S_HID + (8u << 20))
// ---- big (f16, 208MB) layout: spfH overlays encT (dead) and hid (later) ----
#define B_SPFH 0u
#define B_ENCT 0u
#define B_HID  0u
#define B_BITS (128u << 20)
#define B_WT   (136u << 20)
#define B_CB   (144u << 20)
#define WS_BIG ((size_t)B_CB + (64u << 20))

// d_out layout (floats): out0 [4096][3] @0, out1 [4096][4] @12288,
// out2 (mean_spike_rate) [4096][1024] @28672
#define OUT1_F 12288
#define OUT2_F 28672

// one-instruction convert+fma: acc = fl(f32(f16 half of s) * w + acc)
#define FMAMIX_LO(a, s, w)                                                     \
  asm("v_fma_mix_f32 %0, %1, %2, %0 op_sel:[0,0,0] op_sel_hi:[1,0,0]"          \
      : "+v"(a) : "v"(s), "v"(w))
#define FMAMIX_HI(a, s, w)                                                     \
  asm("v_fma_mix_f32 %0, %1, %2, %0 op_sel:[1,0,0] op_sel_hi:[1,0,0]"          \
      : "+v"(a) : "v"(s), "v"(w))

// ---------------------------------------------------------------------------
// Encoder, f32-faithful: z = x @ enc_W, k-sequential FMA chains, kc=384 panel
// split, + bias, sigmoid via CR expf. Output transposed enc_T[i][b].
// ---------------------------------------------------------------------------
__global__ __launch_bounds__(64) void k_genc(const float* __restrict__ x,
                                             const float* __restrict__ W,
                                             const float* __restrict__ bias,
                                             float* __restrict__ encT) {
  const int lane = threadIdx.x;
  const int bg = blockIdx.x & 63;   // b-group of 64
  const int jg = blockIdx.x >> 6;   // j-group of 8 (64 groups)
  const int b = bg * 64 + lane;
  const int j0 = jg * 8;
  const float* xr = x + (size_t)b * 512;
  float accA[8], accB[8];
#pragma unroll
  for (int u = 0; u < 8; ++u) { accA[u] = 0.0f; accB[u] = 0.0f; }
  for (int k = 0; k < 384; ++k) {
    float xv = xr[k];
#pragma unroll
    for (int u = 0; u < 8; ++u) accA[u] = fmaf(xv, W[k * 512 + j0 + u], accA[u]);
  }
  for (int k = 384; k < 512; ++k) {
    float xv = xr[k];
#pragma unroll
    for (int u = 0; u < 8; ++u) accB[u] = fmaf(xv, W[k * 512 + j0 + u], accB[u]);
  }
#pragma unroll
  for (int u = 0; u < 8; ++u) {
    float z = __fadd_rn(__fadd_rn(accA[u], accB[u]), bias[j0 + u]);
    float ef = (float)exp(-(double)z);          // == correctly-rounded expf
    float enc = 1.0f / (1.0f + ef);
    encT[(size_t)(j0 + u) * 4096 + b] = enc;
  }
}

// ---------------------------------------------------------------------------
// Spike bits -> packed [bw][tg][i][8t]: word (bw,tg,i,tt) bit b =
// (noise[b][t][i] < enc[b][i]) f32, t = tg*8+tt. lane = b -> ballot.
// ---------------------------------------------------------------------------
__global__ __launch_bounds__(64) void k_spike(const float* __restrict__ noise,
                                              const float* __restrict__ encT,
                                              u64* __restrict__ bitsP) {
  const int lane = threadIdx.x;
  const int t = blockIdx.x & 31;
  const int bw = blockIdx.x >> 5;   // 64 b-waves
  const int b = bw * 64 + lane;
  const float* nr = noise + ((size_t)b * 32 + t) * 512;
  u64* dst = bitsP + (((size_t)bw * 4 + (t >> 3)) * 512) * 8 + (t & 7);
  for (int i0 = 0; i0 < 512; i0 += 4) {
    float4 nv = *(const float4*)(nr + i0);
    float e0 = encT[(size_t)(i0 + 0) * 4096 + b];
    float e1 = encT[(size_t)(i0 + 1) * 4096 + b];
    float e2 = encT[(size_t)(i0 + 2) * 4096 + b];
    float e3 = encT[(size_t)(i0 + 3) * 4096 + b];
    u64 m0 = __ballot(nv.x < e0);
    u64 m1 = __ballot(nv.y < e1);
    u64 m2 = __ballot(nv.z < e2);
    u64 m3 = __ballot(nv.w < e3);
    if (lane == 0) {
      dst[(i0 + 0) * 8] = m0; dst[(i0 + 1) * 8] = m1;
      dst[(i0 + 2) * 8] = m2; dst[(i0 + 3) * 8] = m3;
    }
  }
}

// ---------------------------------------------------------------------------
// Expand ballots to per-lane f16 {0,1} spikes:
// spfH[(bw,tg,i)][lane][tt] (16B per (i,lane)). 0x3C00 = 1.0h.
// ---------------------------------------------------------------------------
__global__ __launch_bounds__(64) void k_expand16(const u64* __restrict__ bitsP,
                                                 unsigned char* __restrict__ spfH) {
  const int lane = threadIdx.x;
  const int bid = blockIdx.x;       // 2048 = bw(64) x tg(4) x ic(8)
  const int ic = bid & 7;
  const int tg = (bid >> 3) & 3;
  const int bw = bid >> 5;
  const u64* src = bitsP + (((size_t)bw * 4 + tg) * 512) * 8;
  unsigned char* dstb = spfH + (((size_t)bw * 4 + tg) * 512) * 1024 + lane * 16;
  for (int ii = 0; ii < 64; ++ii) {
    const int i = ic * 64 + ii;
    const u64* mr = src + (size_t)i * 8;
    u32 v[4];
#pragma unroll
    for (int q = 0; q < 4; ++q) {
      u32 lo = (u32)((mr[2 * q] >> lane) & 1ULL) ? 0x3C00u : 0u;
      u32 hi = (u32)((mr[2 * q + 1] >> lane) & 1ULL) ? 0x3C000000u : 0u;
      v[q] = lo | hi;
    }
    uint4 pk = {v[0], v[1], v[2], v[3]};
    *(uint4*)(dstb + (size_t)i * 1024) = pk;
  }
}

// ---------------------------------------------------------------------------
// Expand ballots to per-lane u8 spikes (r8 fallback path).
// ---------------------------------------------------------------------------
__global__ __launch_bounds__(64) void k_expand8(const u64* __restrict__ bitsP,
                                                unsigned char* __restrict__ spf) {
  const int lane = threadIdx.x;
  const int bid = blockIdx.x;
  const int ic = bid & 7;
  const int tg = (bid >> 3) & 3;
  const int bw = bid >> 5;
  const u64* src = bitsP + (((size_t)bw * 4 + tg) * 512) * 8;
  for (int ii = 0; ii < 64; ++ii) {
    const int i = ic * 64 + ii;
    u64 w = 0;
#pragma unroll
    for (int tt = 0; tt < 8; ++tt) {
      u64 m = src[(size_t)i * 8 + tt];
      w |= ((m >> lane) & 1ULL) << (8 * tt);
    }
    *(u64*)(spf + ((size_t)(tg * 512 + i) * 4096 + bw * 64 + lane) * 8) = w;
  }
}

// ---------------------------------------------------------------------------
// W repack: Wt[slab][i][8] = lif_W[p][i][hs*8 .. hs*8+7], slab = p*128+hs
// ---------------------------------------------------------------------------
__global__ __launch_bounds__(256) void k_wrep(const float* __restrict__ lifW,
                                              float* __restrict__ Wt) {
  int idx = blockIdx.x * 256 + threadIdx.x;   // 262144 = 4p x 128hs x 512i
  int i = idx & 511;
  int hs = (idx >> 9) & 127;
  int p = idx >> 16;
  const float* src = lifW + ((size_t)(p * 512 + i)) * 1024 + hs * 8;
  float4 a = *(const float4*)src;
  float4 c = *(const float4*)(src + 4);
  float* dst = Wt + (((size_t)(p * 128 + hs)) * 512 + (size_t)i) * 8;
  *(float4*)dst = a;
  *(float4*)(dst + 4) = c;
}

// ---------------------------------------------------------------------------
// pathway selection: softmax(x @ sel_W + sel_b) -> out1 f32
// ---------------------------------------------------------------------------
__global__ __launch_bounds__(256) void k_sel(const float* __restrict__ x,
                                             const float* __restrict__ selW,
                                             const float* __restrict__ selB,
                                             float* __restrict__ out1) {
  int b = blockIdx.x * 256 + threadIdx.x;
  const float* xr = x + (size_t)b * 512;
  double a0 = 0, a1 = 0, a2 = 0, a3 = 0;
  for (int k = 0; k < 512; ++k) {
    double xv = (double)xr[k];
    float4 w = *(const float4*)(selW + k * 4);
    a0 = fma(xv, (double)w.x, a0);
    a1 = fma(xv, (double)w.y, a1);
    a2 = fma(xv, (double)w.z, a2);
    a3 = fma(xv, (double)w.w, a3);
  }
  a0 += (double)selB[0]; a1 += (double)selB[1];
  a2 += (double)selB[2]; a3 += (double)selB[3];
  double m = fmax(fmax(a0, a1), fmax(a2, a3));
  double e0 = exp(a0 - m), e1 = exp(a1 - m), e2 = exp(a2 - m), e3 = exp(a3 - m);
  double inv = 1.0 / (e0 + e1 + e2 + e3);
  float4 wf = {(float)(e0 * inv), (float)(e1 * inv), (float)(e2 * inv), (float)(e3 * inv)};
  *(float4*)(out1 + (size_t)b * 4) = wf;
}

// ---------------------------------------------------------------------------
// Fused LIF (f16 spf + fma_mix), 8h x 8t wave tile, lane = b. Per i:
// 1 per-lane dwordx4 (8 f16 spikes) + 2 uniform float4 (W row) + 64 fma_mix.
// fma_mix: f16->f32 convert (exact on {0,1}) + f32 fma, single rounding ==
// fl(sp*w + acc) == reference sequential-i chain. Bit-identical.
// ---------------------------------------------------------------------------
__global__ __launch_bounds__(64, 4) void k_lif16(const float* __restrict__ Wt,
                                                 const float* __restrict__ lifB,
                                                 const unsigned char* __restrict__ spfH,
                                                 u32* __restrict__ cb) {
  const int lane = threadIdx.x;
  const int bid = blockIdx.x;          // 32768 = 64 bw x 512 slab
  const int slab = bid & 511;          // p*128 + hs
  const int bw = bid >> 9;
  const int p = slab >> 7;
  const int h0 = (slab & 127) * 8;
  const int b0 = bw * 64;
  const float* wbase = Wt + (size_t)slab * 512 * 8;
  const float* biasp = lifB + p * 1024 + h0;

  float mem[8], bias_r[8];
  u32 cbits[8];
#pragma unroll
  for (int h = 0; h < 8; ++h) {
    mem[h] = 0.0f; cbits[h] = 0u;
    bias_r[h] = biasp[h];
  }

#pragma unroll 1
  for (int tg = 0; tg < 4; ++tg) {
    float acc[8][8];
#pragma unroll
    for (int tt = 0; tt < 8; ++tt)
#pragma unroll
      for (int h = 0; h < 8; ++h) acc[tt][h] = 0.0f;

    const unsigned char* sb =
        spfH + (((size_t)bw * 4 + tg) * 512) * 1024 + lane * 16;

#pragma unroll 2
    for (int i = 0; i < 512; ++i) {
      uint4 sp = *(const uint4*)(sb + (size_t)i * 1024);  // per-lane, coalesced
      float4 w0 = *(const float4*)(wbase + i * 8);        // uniform broadcast
      float4 w1 = *(const float4*)(wbase + i * 8 + 4);
      float wf[8] = {w0.x, w0.y, w0.z, w0.w, w1.x, w1.y, w1.z, w1.w};
      u32 sq[4] = {sp.x, sp.y, sp.z, sp.w};
#pragma unroll
      for (int q = 0; q < 4; ++q) {
#pragma unroll
        for (int h = 0; h < 8; ++h) FMAMIX_LO(acc[2 * q][h], sq[q], wf[h]);
#pragma unroll
        for (int h = 0; h < 8; ++h) FMAMIX_HI(acc[2 * q + 1][h], sq[q], wf[h]);
      }
    }
    // membrane update, reference op order (all f32, no contraction)
#pragma unroll
    for (int tt = 0; tt < 8; ++tt) {
      const int t = tg * 8 + tt;
#pragma unroll
      for (int h = 0; h < 8; ++h) {
        float c = __fadd_rn(acc[tt][h], bias_r[h]);
        float mo = mem[h];
        bool blocked = (__float_as_uint(mo) == 0x80000000u);
        float mn = __fadd_rn(__fmul_rn(mo, 0.9f), c);
        bool sp = (mn >= 1.0f) && (!blocked);
        mem[h] = sp ? -0.0f : mn;
        cbits[h] |= (sp ? 1u : 0u) << t;
      }
    }
  }
  u32* dst = cb + ((size_t)p * 4096 + b0 + lane) * 1024 + h0;
  uint4 v0 = {cbits[0], cbits[1], cbits[2], cbits[3]};
  uint4 v1 = {cbits[4], cbits[5], cbits[6], cbits[7]};
  *(uint4*)dst = v0;
  *(uint4*)(dst + 4) = v1;
}

// ---------------------------------------------------------------------------
// Fused LIF (r8 u8 fallback). Identical arithmetic.
// ---------------------------------------------------------------------------
__global__ __launch_bounds__(64, 4) void k_lif8(const float* __restrict__ Wt,
                                                const float* __restrict__ lifB,
                                                const unsigned char* __restrict__ spf,
                                                u32* __restrict__ cb) {
  const int lane = threadIdx.x;
  const int bid = blockIdx.x;
  const int slab = bid & 511;
  const int bw = bid >> 9;
  const int p = slab >> 7;
  const int h0 = (slab & 127) * 8;
  const int b0 = bw * 64;
  const float* wbase = Wt + (size_t)slab * 512 * 8;
  const float* biasp = lifB + p * 1024 + h0;

  float mem[8], bias_r[8];
  u32 cbits[8];
#pragma unroll
  for (int h = 0; h < 8; ++h) {
    mem[h] = 0.0f; cbits[h] = 0u;
    bias_r[h] = biasp[h];
  }

#pragma unroll 1
  for (int tg = 0; tg < 4; ++tg) {
    float acc[8][8];
#pragma unroll
    for (int tt = 0; tt < 8; ++tt)
#pragma unroll
      for (int h = 0; h < 8; ++h) acc[tt][h] = 0.0f;

    const unsigned char* sb = spf + ((size_t)(tg * 512) * 4096 + b0 + lane) * 8;

#pragma unroll 2
    for (int i = 0; i < 512; ++i) {
      u64 sv = *(const u64*)(sb + (size_t)i * 32768);
      float4 w0 = *(const float4*)(wbase + i * 8);
      float4 w1 = *(const float4*)(wbase + i * 8 + 4);
      u32 lo = (u32)sv, hi = (u32)(sv >> 32);
      float sarr[8] = {(float)(lo & 0xffu),        (float)((lo >> 8) & 0xffu),
                       (float)((lo >> 16) & 0xffu), (float)(lo >> 24),
                       (float)(hi & 0xffu),        (float)((hi >> 8) & 0xffu),
                       (float)((hi >> 16) & 0xffu), (float)(hi >> 24)};
#pragma unroll
      for (int tt = 0; tt < 8; ++tt) {
        float sp = sarr[tt];
        acc[tt][0] = fmaf(w0.x, sp, acc[tt][0]);
        acc[tt][1] = fmaf(w0.y, sp, acc[tt][1]);
        acc[tt][2] = fmaf(w0.z, sp, acc[tt][2]);
        acc[tt][3] = fmaf(w0.w, sp, acc[tt][3]);
        acc[tt][4] = fmaf(w1.x, sp, acc[tt][4]);
        acc[tt][5] = fmaf(w1.y, sp, acc[tt][5]);
        acc[tt][6] = fmaf(w1.z, sp, acc[tt][6]);
        acc[tt][7] = fmaf(w1.w, sp, acc[tt][7]);
      }
    }
#pragma unroll
    for (int tt = 0; tt < 8; ++tt) {
      const int t = tg * 8 + tt;
#pragma unroll
      for (int h = 0; h < 8; ++h) {
        float c = __fadd_rn(acc[tt][h], bias_r[h]);
        float mo = mem[h];
        bool blocked = (__float_as_uint(mo) == 0x80000000u);
        float mn = __fadd_rn(__fmul_rn(mo, 0.9f), c);
        bool sp = (mn >= 1.0f) && (!blocked);
        mem[h] = sp ? -0.0f : mn;
        cbits[h] |= (sp ? 1u : 0u) << t;
      }
    }
  }
  u32* dst = cb + ((size_t)p * 4096 + b0 + lane) * 1024 + h0;
  uint4 v0 = {cbits[0], cbits[1], cbits[2], cbits[3]};
  uint4 v1 = {cbits[4], cbits[5], cbits[6], cbits[7]};
  *(uint4*)dst = v0;
  *(uint4*)(dst + 4) = v1;
}

// ---------------------------------------------------------------------------
// msr[b][h]: faithful f32: per t: s = p-ascending chain; acc = fl(acc+s); /32.
// ---------------------------------------------------------------------------
__global__ __launch_bounds__(256) void k_reduce(const u32* __restrict__ cb,
                                                const float* __restrict__ w,
                                                float* __restrict__ msr) {
  int idx = blockIdx.x * 256 + threadIdx.x;  // 4194304
  int h = idx & 1023;
  int b = idx >> 10;
  float4 wv = *(const float4*)(w + (size_t)b * 4);
  u32 c0 = cb[((size_t)0 * 4096 + b) * 1024 + h];
  u32 c1 = cb[((size_t)1 * 4096 + b) * 1024 + h];
  u32 c2 = cb[((size_t)2 * 4096 + b) * 1024 + h];
  u32 c3 = cb[((size_t)3 * 4096 + b) * 1024 + h];
  float acc = 0.0f;
#pragma unroll
  for (int t = 0; t < 32; ++t) {
    float s = ((c0 >> t) & 1u) ? wv.x : 0.0f;
    s = __fadd_rn(s, ((c1 >> t) & 1u) ? wv.y : 0.0f);
    s = __fadd_rn(s, ((c2 >> t) & 1u) ? wv.z : 0.0f);
    s = __fadd_rn(s, ((c3 >> t) & 1u) ? wv.w : 0.0f);
    acc = __fadd_rn(acc, s);
  }
  msr[(size_t)b * 1024 + h] = acc * 0.03125f;  // /32 exact
}

// ---------------------------------------------------------------------------
// f32 GEMM + relu (head):  out = relu(A[M,K] @ W[K,N] + bias)
// ---------------------------------------------------------------------------
__global__ __launch_bounds__(256) void k_gemm_relu(const float* __restrict__ A, int lda,
                                                   const float* __restrict__ W, int ldw,
                                                   const float* __restrict__ bias,
                                                   float* __restrict__ out, int ldo, int K) {
  __shared__ float As[16][65];
  __shared__ float Bs[16][64];
  const int tid = threadIdx.x;
  const int tx = tid & 15, ty = tid >> 4;
  const int n0 = blockIdx.x * 64, m0 = blockIdx.y * 64;
  const int sm = tid >> 2, skq = tid & 3;
  float acc[4][4] = {};
  for (int k0 = 0; k0 < K; k0 += 16) {
    float4 av = *(const float4*)(A + (size_t)(m0 + sm) * lda + k0 + skq * 4);
    As[skq * 4 + 0][sm] = av.x;
    As[skq * 4 + 1][sm] = av.y;
    As[skq * 4 + 2][sm] = av.z;
    As[skq * 4 + 3][sm] = av.w;
#pragma unroll
    for (int j = 0; j < 4; ++j) {
      int k = j * 4 + (tid >> 6);
      int n = tid & 63;
      Bs[k][n] = W[(size_t)(k0 + k) * ldw + n0 + n];
    }
    __syncthreads();
#pragma unroll
    for (int k = 0; k < 16; ++k) {
      float a[4], bb[4];
#pragma unroll
      for (int i = 0; i < 4; ++i) a[i] = As[k][ty * 4 + i];
#pragma unroll
      for (int i = 0; i < 4; ++i) bb[i] = Bs[k][tx * 4 + i];
#pragma unroll
      for (int i = 0; i < 4; ++i)
#pragma unroll
        for (int ii = 0; ii < 4; ++ii) acc[i][ii] = fmaf(a[i], bb[ii], acc[i][ii]);
    }
    __syncthreads();
  }
#pragma unroll
  for (int i = 0; i < 4; ++i)
#pragma unroll
    for (int ii = 0; ii < 4; ++ii) {
      float v = fmaxf(acc[i][ii] + bias[n0 + tx * 4 + ii], 0.0f);
      out[(size_t)(m0 + ty * 4 + i) * ldo + n0 + tx * 4 + ii] = v;
    }
}

// ---------------------------------------------------------------------------
// out0 = hid @ out_W2 + b2   (one thread per b)
// ---------------------------------------------------------------------------
__global__ __launch_bounds__(256) void k_head2(const float* __restrict__ hid,
                                               const float* __restrict__ W2,
                                               const float* __restrict__ b2,
                                               float* __restrict__ out0) {
  __shared__ float w2s[512][3];
  int tid = threadIdx.x;
  for (int i = tid; i < 1536; i += 256) ((float*)w2s)[i] = W2[i];
  __syncthreads();
  int b = blockIdx.x * 256 + tid;
  const float* hr = hid + (size_t)b * 512;
  float a0 = 0, a1 = 0, a2 = 0;
  for (int j = 0; j < 512; ++j) {
    float h = hr[j];
    a0 = fmaf(h, w2s[j][0], a0);
    a1 = fmaf(h, w2s[j][1], a1);
    a2 = fmaf(h, w2s[j][2], a2);
  }
  out0[b * 3 + 0] = a0 + b2[0];
  out0[b * 3 + 1] = a1 + b2[1];
  out0[b * 3 + 2] = a2 + b2[2];
}

// ---------------------------------------------------------------------------
extern "C" void kernel_launch(void* const* d_in, const int* in_sizes, int n_in,
                              void* d_out, int out_size, void* d_ws, size_t ws_size,
                              hipStream_t stream) {
  const float* x = (const float*)d_in[0];
  const float* noise = (const float*)d_in[1];
  const float* encW = (const float*)d_in[3];
  const float* encB = (const float*)d_in[4];
  const float* selW = (const float*)d_in[5];
  const float* selB = (const float*)d_in[6];
  const float* lifW = (const float*)d_in[7];
  const float* lifB = (const float*)d_in[8];
  const float* W1 = (const float*)d_in[9];
  const float* b1 = (const float*)d_in[10];
  const float* W2 = (const float*)d_in[11];
  const float* b2 = (const float*)d_in[12];
  float* out = (float*)d_out;
  unsigned char* ws = (unsigned char*)d_ws;

  if (ws_size >= WS_BIG) {
    // f16 fma_mix path
    float* encT = (float*)(ws + B_ENCT);
    unsigned char* spfH = ws + B_SPFH;
    u64* bitsP = (u64*)(ws + B_BITS);
    float* Wt = (float*)(ws + B_WT);
    u32* cb = (u32*)(ws + B_CB);
    float* hid = (float*)(ws + B_HID);

    k_genc<<<dim3(4096), 64, 0, stream>>>(x, encW, encB, encT);
    k_sel<<<dim3(16), 256, 0, stream>>>(x, selW, selB, out + OUT1_F);
    k_wrep<<<dim3(1024), 256, 0, stream>>>(lifW, Wt);
    k_spike<<<dim3(2048), 64, 0, stream>>>(noise, encT, bitsP);
    k_expand16<<<dim3(2048), 64, 0, stream>>>(bitsP, spfH);  // clobbers encT (dead)
    k_lif16<<<dim3(32768), 64, 0, stream>>>(Wt, lifB, spfH, cb);
    k_reduce<<<dim3(16384), 256, 0, stream>>>(cb, out + OUT1_F, out + OUT2_F);
    k_gemm_relu<<<dim3(8, 64), 256, 0, stream>>>(out + OUT2_F, 1024, W1, 512, b1,
                                                 hid, 512, 1024);  // hid overlays spfH (dead)
    k_head2<<<dim3(16), 256, 0, stream>>>(hid, W2, b2, out);
    return;
  }

  if (ws_size < WS_SMALL) {
    fprintf(stderr, "kernel_launch: ws too small (%zu < %zu)\n", ws_size, (size_t)WS_SMALL);
    return;
  }
  // r8 u8 fallback path
  float* encT = (float*)(ws + S_ENCT);
  u64* bitsP = (u64*)(ws + S_BITS);
  float* Wt = (float*)(ws + S_WT);
  unsigned char* spf = ws + S_SPF;
  u32* cb = (u32*)(ws + S_CB);
  float* hid = (float*)(ws + S_HID);

  k_genc<<<dim3(4096), 64, 0, stream>>>(x, encW, encB, encT);
  k_sel<<<dim3(16), 256, 0, stream>>>(x, selW, selB, out + OUT1_F);
  k_wrep<<<dim3(1024), 256, 0, stream>>>(lifW, Wt);
  k_spike<<<dim3(2048), 64, 0, stream>>>(noise, encT, bitsP);
  k_expand8<<<dim3(2048), 64, 0, stream>>>(bitsP, spf);
  k_lif8<<<dim3(32768), 64, 0, stream>>>(Wt, lifB, spf, cb);
  k_reduce<<<dim3(16384), 256, 0, stream>>>(cb, out + OUT1_F, out + OUT2_F);
  k_gemm_relu<<<dim3(8, 64), 256, 0, stream>>>(out + OUT2_F, 1024, W1, 512, b1, hid, 512, 1024);
  k_head2<<<dim3(16), 256, 0, stream>>>(hid, W2, b2, out);
}

// Round 10
// 6702.064 us; speedup vs baseline: 1.4354x; 1.4354x over previous
//
#include <hip/hip_runtime.h>
#include <hip/hip_bf16.h>
#include <stdint.h>
#include <cstdio>
#include <math.h>

// ---------------------------------------------------------------------------
// SpikingTradingAgent on MI355X — round 10.
// Numerics FROZEN (rounds 4-9 passed, absmax 1.07e-2): f32-faithful
// sequential-i einsum chain, f32 membrane update in reference op order,
// -0.0 refractory encoding, CR-exp sigmoid encoder, ballot spike bits.
//
// Round-10 change (scheduling only, bit-identical arithmetic):
// r8 = ~95% of the chip's scalar-VALU issue ceiling (3.1 cy/instr == m07's
// 103/157 TF). r9 proved fma_mix is half-rate -> regression. Remaining lever:
// v_pk_fma_f32 = TWO independent IEEE f32 FMAs per instruction (packed).
// Spikes stored as f32 {0,1.0} in a 128MB buffer, processed in two bw-passes
// (fits the confirmed 208MB workspace). Inner loop per i: 4 sp-pair loads +
// 4 uniform W-pair loads + 32 pk_fma (op_sel picks sp lo/hi for even/odd tt,
// no dup movs) ~= 43 instr vs r8's ~72. Each pk half = fl(w*sp + acc) ==
// the frozen chain -> bit-identical.
// ---------------------------------------------------------------------------

typedef unsigned int u32;
typedef unsigned long long u64;
typedef float f32x2 __attribute__((ext_vector_type(2)));

// ---- big layout (208 MB, confirmed available in r9) ----
#define P_SPF  0u                          // f32 pass buffer 128 MiB
#define P_ENCT 0u                          // encT overlays spf (dead before expand)
#define P_HID  0u                          // hid overlays spf (after lif)
#define P_BITS (128u << 20)                // u64 [64][4][512][8]   8 MiB
#define P_WT   (136u << 20)                // f32 [512][512][8]     8 MiB
#define P_CB   (144u << 20)                // u32 [4][4096][1024]  64 MiB
#define WS_BIG ((size_t)P_CB + (64u << 20))
// ---- small fallback (r8 layout, 160 MB) ----
#define S_ENCT 0u
#define S_BITS (8u << 20)
#define S_WT   (16u << 20)
#define S_SPF  (24u << 20)
#define S_CB   (88u << 20)
#define S_HID  (152u << 20)
#define WS_SMALL ((size_t)S_HID + (8u << 20))

// d_out layout (floats): out0 [4096][3] @0, out1 [4096][4] @12288,
// out2 (mean_spike_rate) [4096][1024] @28672
#define OUT1_F 12288
#define OUT2_F 28672

// packed dual f32 fma: even tt (sp in lo), odd tt (sp in hi)
#define PKFMA_E(a, w, s)                                                       \
  asm("v_pk_fma_f32 %0, %1, %2, %0 op_sel:[0,0,0] op_sel_hi:[1,0,1]"           \
      : "+v"(a) : "v"(w), "v"(s))
#define PKFMA_O(a, w, s)                                                       \
  asm("v_pk_fma_f32 %0, %1, %2, %0 op_sel:[0,1,0] op_sel_hi:[1,1,1]"           \
      : "+v"(a) : "v"(w), "v"(s))

// ---------------------------------------------------------------------------
// Encoder, f32-faithful: z = x @ enc_W, k-sequential FMA chains, kc=384 panel
// split, + bias, sigmoid via CR expf. Output transposed enc_T[i][b].
// ---------------------------------------------------------------------------
__global__ __launch_bounds__(64) void k_genc(const float* __restrict__ x,
                                             const float* __restrict__ W,
                                             const float* __restrict__ bias,
                                             float* __restrict__ encT) {
  const int lane = threadIdx.x;
  const int bg = blockIdx.x & 63;   // b-group of 64
  const int jg = blockIdx.x >> 6;   // j-group of 8 (64 groups)
  const int b = bg * 64 + lane;
  const int j0 = jg * 8;
  const float* xr = x + (size_t)b * 512;
  float accA[8], accB[8];
#pragma unroll
  for (int u = 0; u < 8; ++u) { accA[u] = 0.0f; accB[u] = 0.0f; }
  for (int k = 0; k < 384; ++k) {
    float xv = xr[k];
#pragma unroll
    for (int u = 0; u < 8; ++u) accA[u] = fmaf(xv, W[k * 512 + j0 + u], accA[u]);
  }
  for (int k = 384; k < 512; ++k) {
    float xv = xr[k];
#pragma unroll
    for (int u = 0; u < 8; ++u) accB[u] = fmaf(xv, W[k * 512 + j0 + u], accB[u]);
  }
#pragma unroll
  for (int u = 0; u < 8; ++u) {
    float z = __fadd_rn(__fadd_rn(accA[u], accB[u]), bias[j0 + u]);
    float ef = (float)exp(-(double)z);          // == correctly-rounded expf
    float enc = 1.0f / (1.0f + ef);
    encT[(size_t)(j0 + u) * 4096 + b] = enc;
  }
}

// ---------------------------------------------------------------------------
// Spike bits -> packed [bw][tg][i][8t]: word (bw,tg,i,tt) bit b =
// (noise[b][t][i] < enc[b][i]) f32, t = tg*8+tt. lane = b -> ballot.
// ---------------------------------------------------------------------------
__global__ __launch_bounds__(64) void k_spike(const float* __restrict__ noise,
                                              const float* __restrict__ encT,
                                              u64* __restrict__ bitsP) {
  const int lane = threadIdx.x;
  const int t = blockIdx.x & 31;
  const int bw = blockIdx.x >> 5;   // 64 b-waves
  const int b = bw * 64 + lane;
  const float* nr = noise + ((size_t)b * 32 + t) * 512;
  u64* dst = bitsP + (((size_t)bw * 4 + (t >> 3)) * 512) * 8 + (t & 7);
  for (int i0 = 0; i0 < 512; i0 += 4) {
    float4 nv = *(const float4*)(nr + i0);
    float e0 = encT[(size_t)(i0 + 0) * 4096 + b];
    float e1 = encT[(size_t)(i0 + 1) * 4096 + b];
    float e2 = encT[(size_t)(i0 + 2) * 4096 + b];
    float e3 = encT[(size_t)(i0 + 3) * 4096 + b];
    u64 m0 = __ballot(nv.x < e0);
    u64 m1 = __ballot(nv.y < e1);
    u64 m2 = __ballot(nv.z < e2);
    u64 m3 = __ballot(nv.w < e3);
    if (lane == 0) {
      dst[(i0 + 0) * 8] = m0; dst[(i0 + 1) * 8] = m1;
      dst[(i0 + 2) * 8] = m2; dst[(i0 + 3) * 8] = m3;
    }
  }
}

// ---------------------------------------------------------------------------
// Expand ballots to per-lane f32 {0,1.0} spikes for a 32-bw pass:
// spf32[(bwl*4+tg)][i][lane][tt] (32B per (i,lane)).
// ---------------------------------------------------------------------------
__global__ __launch_bounds__(64) void k_expand32(const u64* __restrict__ bitsP,
                                                 float* __restrict__ spf32,
                                                 int bw0) {
  const int lane = threadIdx.x;
  const int bid = blockIdx.x;       // 1024 = bwl(32) x tg(4) x ic(8)
  const int ic = bid & 7;
  const int tg = (bid >> 3) & 3;
  const int bwl = bid >> 5;         // 0..31
  const int bw = bw0 + bwl;
  const u64* src = bitsP + (((size_t)bw * 4 + tg) * 512) * 8;
  float* dst = spf32 + (size_t)(bwl * 4 + tg) * 262144 + lane * 8;
  for (int ii = 0; ii < 64; ++ii) {
    const int i = ic * 64 + ii;
    const u64* mr = src + (size_t)i * 8;
    float v[8];
#pragma unroll
    for (int tt = 0; tt < 8; ++tt)
      v[tt] = ((mr[tt] >> lane) & 1ULL) ? 1.0f : 0.0f;
    float4 a = {v[0], v[1], v[2], v[3]};
    float4 c = {v[4], v[5], v[6], v[7]};
    *(float4*)(dst + (size_t)i * 512) = a;
    *(float4*)(dst + (size_t)i * 512 + 4) = c;
  }
}

// ---------------------------------------------------------------------------
// Expand ballots to per-lane u8 spikes (r8 fallback path).
// ---------------------------------------------------------------------------
__global__ __launch_bounds__(64) void k_expand8(const u64* __restrict__ bitsP,
                                                unsigned char* __restrict__ spf) {
  const int lane = threadIdx.x;
  const int bid = blockIdx.x;
  const int ic = bid & 7;
  const int tg = (bid >> 3) & 3;
  const int bw = bid >> 5;
  const u64* src = bitsP + (((size_t)bw * 4 + tg) * 512) * 8;
  for (int ii = 0; ii < 64; ++ii) {
    const int i = ic * 64 + ii;
    u64 w = 0;
#pragma unroll
    for (int tt = 0; tt < 8; ++tt) {
      u64 m = src[(size_t)i * 8 + tt];
      w |= ((m >> lane) & 1ULL) << (8 * tt);
    }
    *(u64*)(spf + ((size_t)(tg * 512 + i) * 4096 + bw * 64 + lane) * 8) = w;
  }
}

// ---------------------------------------------------------------------------
// W repack: Wt[slab][i][8] = lif_W[p][i][hs*8 .. hs*8+7], slab = p*128+hs
// ---------------------------------------------------------------------------
__global__ __launch_bounds__(256) void k_wrep(const float* __restrict__ lifW,
                                              float* __restrict__ Wt) {
  int idx = blockIdx.x * 256 + threadIdx.x;   // 262144 = 4p x 128hs x 512i
  int i = idx & 511;
  int hs = (idx >> 9) & 127;
  int p = idx >> 16;
  const float* src = lifW + ((size_t)(p * 512 + i)) * 1024 + hs * 8;
  float4 a = *(const float4*)src;
  float4 c = *(const float4*)(src + 4);
  float* dst = Wt + (((size_t)(p * 128 + hs)) * 512 + (size_t)i) * 8;
  *(float4*)dst = a;
  *(float4*)(dst + 4) = c;
}

// ---------------------------------------------------------------------------
// pathway selection: softmax(x @ sel_W + sel_b) -> out1 f32
// ---------------------------------------------------------------------------
__global__ __launch_bounds__(256) void k_sel(const float* __restrict__ x,
                                             const float* __restrict__ selW,
                                             const float* __restrict__ selB,
                                             float* __restrict__ out1) {
  int b = blockIdx.x * 256 + threadIdx.x;
  const float* xr = x + (size_t)b * 512;
  double a0 = 0, a1 = 0, a2 = 0, a3 = 0;
  for (int k = 0; k < 512; ++k) {
    double xv = (double)xr[k];
    float4 w = *(const float4*)(selW + k * 4);
    a0 = fma(xv, (double)w.x, a0);
    a1 = fma(xv, (double)w.y, a1);
    a2 = fma(xv, (double)w.z, a2);
    a3 = fma(xv, (double)w.w, a3);
  }
  a0 += (double)selB[0]; a1 += (double)selB[1];
  a2 += (double)selB[2]; a3 += (double)selB[3];
  double m = fmax(fmax(a0, a1), fmax(a2, a3));
  double e0 = exp(a0 - m), e1 = exp(a1 - m), e2 = exp(a2 - m), e3 = exp(a3 - m);
  double inv = 1.0 / (e0 + e1 + e2 + e3);
  float4 wf = {(float)(e0 * inv), (float)(e1 * inv), (float)(e2 * inv), (float)(e3 * inv)};
  *(float4*)(out1 + (size_t)b * 4) = wf;
}

// ---------------------------------------------------------------------------
// Fused LIF, pk_fma edition. 8h x 8t wave tile, lane = b, one 32-bw pass.
// Per i: 4 per-lane f32x2 sp loads + 4 uniform f32x2 W loads + 32 pk_fma.
// Each pk half = fl(w*sp + acc) -> bit-identical sequential-i chains.
// ---------------------------------------------------------------------------
__global__ __launch_bounds__(64, 4) void k_lifpk(const float* __restrict__ Wt,
                                                 const float* __restrict__ lifB,
                                                 const float* __restrict__ spf32,
                                                 u32* __restrict__ cb,
                                                 int bw0) {
  const int lane = threadIdx.x;
  const int bid = blockIdx.x;          // 16384 = 32 bwl x 512 slab
  const int slab = bid & 511;          // p*128 + hs
  const int bwl = bid >> 9;            // 0..31
  const int bw = bw0 + bwl;
  const int p = slab >> 7;
  const int h0 = (slab & 127) * 8;
  const int b0 = bw * 64;
  const float* wbase = Wt + (size_t)slab * 512 * 8;
  const float* biasp = lifB + p * 1024 + h0;

  float mem[8], bias_r[8];
  u32 cbits[8];
#pragma unroll
  for (int h = 0; h < 8; ++h) {
    mem[h] = 0.0f; cbits[h] = 0u;
    bias_r[h] = biasp[h];
  }

#pragma unroll 1
  for (int tg = 0; tg < 4; ++tg) {
    f32x2 acc[8][4];
#pragma unroll
    for (int tt = 0; tt < 8; ++tt)
#pragma unroll
      for (int q = 0; q < 4; ++q) acc[tt][q] = (f32x2){0.0f, 0.0f};

    const float* sb = spf32 + (size_t)(bwl * 4 + tg) * 262144 + lane * 8;

#pragma unroll 2
    for (int i = 0; i < 512; ++i) {
      const float* sp = sb + (size_t)i * 512;     // per-lane, coalesced
      f32x2 s01 = *(const f32x2*)(sp + 0);        // (tt0, tt1)
      f32x2 s23 = *(const f32x2*)(sp + 2);
      f32x2 s45 = *(const f32x2*)(sp + 4);
      f32x2 s67 = *(const f32x2*)(sp + 6);
      const float* wr = wbase + i * 8;            // uniform broadcast
      f32x2 w0 = *(const f32x2*)(wr + 0);
      f32x2 w1 = *(const f32x2*)(wr + 2);
      f32x2 w2 = *(const f32x2*)(wr + 4);
      f32x2 w3 = *(const f32x2*)(wr + 6);
      f32x2 wq[4] = {w0, w1, w2, w3};
#pragma unroll
      for (int q = 0; q < 4; ++q) {
        PKFMA_E(acc[0][q], wq[q], s01);
        PKFMA_O(acc[1][q], wq[q], s01);
        PKFMA_E(acc[2][q], wq[q], s23);
        PKFMA_O(acc[3][q], wq[q], s23);
        PKFMA_E(acc[4][q], wq[q], s45);
        PKFMA_O(acc[5][q], wq[q], s45);
        PKFMA_E(acc[6][q], wq[q], s67);
        PKFMA_O(acc[7][q], wq[q], s67);
      }
    }
    // membrane update, reference op order (all f32, no contraction)
#pragma unroll
    for (int tt = 0; tt < 8; ++tt) {
      const int t = tg * 8 + tt;
#pragma unroll
      for (int q = 0; q < 4; ++q) {
#pragma unroll
        for (int half = 0; half < 2; ++half) {
          const int h = q * 2 + half;
          float av = half ? acc[tt][q].y : acc[tt][q].x;
          float c = __fadd_rn(av, bias_r[h]);
          float mo = mem[h];
          bool blocked = (__float_as_uint(mo) == 0x80000000u);
          float mn = __fadd_rn(__fmul_rn(mo, 0.9f), c);
          bool sp = (mn >= 1.0f) && (!blocked);
          mem[h] = sp ? -0.0f : mn;
          cbits[h] |= (sp ? 1u : 0u) << t;
        }
      }
    }
  }
  u32* dst = cb + ((size_t)p * 4096 + b0 + lane) * 1024 + h0;
  uint4 v0 = {cbits[0], cbits[1], cbits[2], cbits[3]};
  uint4 v1 = {cbits[4], cbits[5], cbits[6], cbits[7]};
  *(uint4*)dst = v0;
  *(uint4*)(dst + 4) = v1;
}

// ---------------------------------------------------------------------------
// Fused LIF (r8 u8 fallback). Identical arithmetic.
// ---------------------------------------------------------------------------
__global__ __launch_bounds__(64, 4) void k_lif8(const float* __restrict__ Wt,
                                                const float* __restrict__ lifB,
                                                const unsigned char* __restrict__ spf,
                                                u32* __restrict__ cb) {
  const int lane = threadIdx.x;
  const int bid = blockIdx.x;
  const int slab = bid & 511;
  const int bw = bid >> 9;
  const int p = slab >> 7;
  const int h0 = (slab & 127) * 8;
  const int b0 = bw * 64;
  const float* wbase = Wt + (size_t)slab * 512 * 8;
  const float* biasp = lifB + p * 1024 + h0;

  float mem[8], bias_r[8];
  u32 cbits[8];
#pragma unroll
  for (int h = 0; h < 8; ++h) {
    mem[h] = 0.0f; cbits[h] = 0u;
    bias_r[h] = biasp[h];
  }

#pragma unroll 1
  for (int tg = 0; tg < 4; ++tg) {
    float acc[8][8];
#pragma unroll
    for (int tt = 0; tt < 8; ++tt)
#pragma unroll
      for (int h = 0; h < 8; ++h) acc[tt][h] = 0.0f;

    const unsigned char* sb = spf + ((size_t)(tg * 512) * 4096 + b0 + lane) * 8;

#pragma unroll 2
    for (int i = 0; i < 512; ++i) {
      u64 sv = *(const u64*)(sb + (size_t)i * 32768);
      float4 w0 = *(const float4*)(wbase + i * 8);
      float4 w1 = *(const float4*)(wbase + i * 8 + 4);
      u32 lo = (u32)sv, hi = (u32)(sv >> 32);
      float sarr[8] = {(float)(lo & 0xffu),        (float)((lo >> 8) & 0xffu),
                       (float)((lo >> 16) & 0xffu), (float)(lo >> 24),
                       (float)(hi & 0xffu),        (float)((hi >> 8) & 0xffu),
                       (float)((hi >> 16) & 0xffu), (float)(hi >> 24)};
#pragma unroll
      for (int tt = 0; tt < 8; ++tt) {
        float sp = sarr[tt];
        acc[tt][0] = fmaf(w0.x, sp, acc[tt][0]);
        acc[tt][1] = fmaf(w0.y, sp, acc[tt][1]);
        acc[tt][2] = fmaf(w0.z, sp, acc[tt][2]);
        acc[tt][3] = fmaf(w0.w, sp, acc[tt][3]);
        acc[tt][4] = fmaf(w1.x, sp, acc[tt][4]);
        acc[tt][5] = fmaf(w1.y, sp, acc[tt][5]);
        acc[tt][6] = fmaf(w1.z, sp, acc[tt][6]);
        acc[tt][7] = fmaf(w1.w, sp, acc[tt][7]);
      }
    }
#pragma unroll
    for (int tt = 0; tt < 8; ++tt) {
      const int t = tg * 8 + tt;
#pragma unroll
      for (int h = 0; h < 8; ++h) {
        float c = __fadd_rn(acc[tt][h], bias_r[h]);
        float mo = mem[h];
        bool blocked = (__float_as_uint(mo) == 0x80000000u);
        float mn = __fadd_rn(__fmul_rn(mo, 0.9f), c);
        bool sp = (mn >= 1.0f) && (!blocked);
        mem[h] = sp ? -0.0f : mn;
        cbits[h] |= (sp ? 1u : 0u) << t;
      }
    }
  }
  u32* dst = cb + ((size_t)p * 4096 + b0 + lane) * 1024 + h0;
  uint4 v0 = {cbits[0], cbits[1], cbits[2], cbits[3]};
  uint4 v1 = {cbits[4], cbits[5], cbits[6], cbits[7]};
  *(uint4*)dst = v0;
  *(uint4*)(dst + 4) = v1;
}

// ---------------------------------------------------------------------------
// msr[b][h]: faithful f32: per t: s = p-ascending chain; acc = fl(acc+s); /32.
// ---------------------------------------------------------------------------
__global__ __launch_bounds__(256) void k_reduce(const u32* __restrict__ cb,
                                                const float* __restrict__ w,
                                                float* __restrict__ msr) {
  int idx = blockIdx.x * 256 + threadIdx.x;  // 4194304
  int h = idx & 1023;
  int b = idx >> 10;
  float4 wv = *(const float4*)(w + (size_t)b * 4);
  u32 c0 = cb[((size_t)0 * 4096 + b) * 1024 + h];
  u32 c1 = cb[((size_t)1 * 4096 + b) * 1024 + h];
  u32 c2 = cb[((size_t)2 * 4096 + b) * 1024 + h];
  u32 c3 = cb[((size_t)3 * 4096 + b) * 1024 + h];
  float acc = 0.0f;
#pragma unroll
  for (int t = 0; t < 32; ++t) {
    float s = ((c0 >> t) & 1u) ? wv.x : 0.0f;
    s = __fadd_rn(s, ((c1 >> t) & 1u) ? wv.y : 0.0f);
    s = __fadd_rn(s, ((c2 >> t) & 1u) ? wv.z : 0.0f);
    s = __fadd_rn(s, ((c3 >> t) & 1u) ? wv.w : 0.0f);
    acc = __fadd_rn(acc, s);
  }
  msr[(size_t)b * 1024 + h] = acc * 0.03125f;  // /32 exact
}

// ---------------------------------------------------------------------------
// f32 GEMM + relu (head):  out = relu(A[M,K] @ W[K,N] + bias)
// ---------------------------------------------------------------------------
__global__ __launch_bounds__(256) void k_gemm_relu(const float* __restrict__ A, int lda,
                                                   const float* __restrict__ W, int ldw,
                                                   const float* __restrict__ bias,
                                                   float* __restrict__ out, int ldo, int K) {
  __shared__ float As[16][65];
  __shared__ float Bs[16][64];
  const int tid = threadIdx.x;
  const int tx = tid & 15, ty = tid >> 4;
  const int n0 = blockIdx.x * 64, m0 = blockIdx.y * 64;
  const int sm = tid >> 2, skq = tid & 3;
  float acc[4][4] = {};
  for (int k0 = 0; k0 < K; k0 += 16) {
    float4 av = *(const float4*)(A + (size_t)(m0 + sm) * lda + k0 + skq * 4);
    As[skq * 4 + 0][sm] = av.x;
    As[skq * 4 + 1][sm] = av.y;
    As[skq * 4 + 2][sm] = av.z;
    As[skq * 4 + 3][sm] = av.w;
#pragma unroll
    for (int j = 0; j < 4; ++j) {
      int k = j * 4 + (tid >> 6);
      int n = tid & 63;
      Bs[k][n] = W[(size_t)(k0 + k) * ldw + n0 + n];
    }
    __syncthreads();
#pragma unroll
    for (int k = 0; k < 16; ++k) {
      float a[4], bb[4];
#pragma unroll
      for (int i = 0; i < 4; ++i) a[i] = As[k][ty * 4 + i];
#pragma unroll
      for (int i = 0; i < 4; ++i) bb[i] = Bs[k][tx * 4 + i];
#pragma unroll
      for (int i = 0; i < 4; ++i)
#pragma unroll
        for (int ii = 0; ii < 4; ++ii) acc[i][ii] = fmaf(a[i], bb[ii], acc[i][ii]);
    }
    __syncthreads();
  }
#pragma unroll
  for (int i = 0; i < 4; ++i)
#pragma unroll
    for (int ii = 0; ii < 4; ++ii) {
      float v = fmaxf(acc[i][ii] + bias[n0 + tx * 4 + ii], 0.0f);
      out[(size_t)(m0 + ty * 4 + i) * ldo + n0 + tx * 4 + ii] = v;
    }
}

// ---------------------------------------------------------------------------
// out0 = hid @ out_W2 + b2   (one thread per b)
// ---------------------------------------------------------------------------
__global__ __launch_bounds__(256) void k_head2(const float* __restrict__ hid,
                                               const float* __restrict__ W2,
                                               const float* __restrict__ b2,
                                               float* __restrict__ out0) {
  __shared__ float w2s[512][3];
  int tid = threadIdx.x;
  for (int i = tid; i < 1536; i += 256) ((float*)w2s)[i] = W2[i];
  __syncthreads();
  int b = blockIdx.x * 256 + tid;
  const float* hr = hid + (size_t)b * 512;
  float a0 = 0, a1 = 0, a2 = 0;
  for (int j = 0; j < 512; ++j) {
    float h = hr[j];
    a0 = fmaf(h, w2s[j][0], a0);
    a1 = fmaf(h, w2s[j][1], a1);
    a2 = fmaf(h, w2s[j][2], a2);
  }
  out0[b * 3 + 0] = a0 + b2[0];
  out0[b * 3 + 1] = a1 + b2[1];
  out0[b * 3 + 2] = a2 + b2[2];
}

// ---------------------------------------------------------------------------
extern "C" void kernel_launch(void* const* d_in, const int* in_sizes, int n_in,
                              void* d_out, int out_size, void* d_ws, size_t ws_size,
                              hipStream_t stream) {
  const float* x = (const float*)d_in[0];
  const float* noise = (const float*)d_in[1];
  const float* encW = (const float*)d_in[3];
  const float* encB = (const float*)d_in[4];
  const float* selW = (const float*)d_in[5];
  const float* selB = (const float*)d_in[6];
  const float* lifW = (const float*)d_in[7];
  const float* lifB = (const float*)d_in[8];
  const float* W1 = (const float*)d_in[9];
  const float* b1 = (const float*)d_in[10];
  const float* W2 = (const float*)d_in[11];
  const float* b2 = (const float*)d_in[12];
  float* out = (float*)d_out;
  unsigned char* ws = (unsigned char*)d_ws;

  if (ws_size >= WS_BIG) {
    // pk_fma path, two 32-bw passes over a shared 128MB f32 spike buffer
    float* encT = (float*)(ws + P_ENCT);
    float* spf32 = (float*)(ws + P_SPF);
    u64* bitsP = (u64*)(ws + P_BITS);
    float* Wt = (float*)(ws + P_WT);
    u32* cb = (u32*)(ws + P_CB);
    float* hid = (float*)(ws + P_HID);

    k_genc<<<dim3(4096), 64, 0, stream>>>(x, encW, encB, encT);
    k_sel<<<dim3(16), 256, 0, stream>>>(x, selW, selB, out + OUT1_F);
    k_wrep<<<dim3(1024), 256, 0, stream>>>(lifW, Wt);
    k_spike<<<dim3(2048), 64, 0, stream>>>(noise, encT, bitsP);
    // pass A: bw 0..31  (expand clobbers encT, which is dead now)
    k_expand32<<<dim3(1024), 64, 0, stream>>>(bitsP, spf32, 0);
    k_lifpk<<<dim3(16384), 64, 0, stream>>>(Wt, lifB, spf32, cb, 0);
    // pass B: bw 32..63
    k_expand32<<<dim3(1024), 64, 0, stream>>>(bitsP, spf32, 32);
    k_lifpk<<<dim3(16384), 64, 0, stream>>>(Wt, lifB, spf32, cb, 32);
    k_reduce<<<dim3(16384), 256, 0, stream>>>(cb, out + OUT1_F, out + OUT2_F);
    k_gemm_relu<<<dim3(8, 64), 256, 0, stream>>>(out + OUT2_F, 1024, W1, 512, b1,
                                                 hid, 512, 1024);  // hid overlays spf32 (dead)
    k_head2<<<dim3(16), 256, 0, stream>>>(hid, W2, b2, out);
    return;
  }

  if (ws_size < WS_SMALL) {
    fprintf(stderr, "kernel_launch: ws too small (%zu < %zu)\n", ws_size, (size_t)WS_SMALL);
    return;
  }
  // r8 u8 fallback path
  float* encT = (float*)(ws + S_ENCT);
  u64* bitsP = (u64*)(ws + S_BITS);
  float* Wt = (float*)(ws + S_WT);
  unsigned char* spf = ws + S_SPF;
  u32* cb = (u32*)(ws + S_CB);
  float* hid = (float*)(ws + S_HID);

  k_genc<<<dim3(4096), 64, 0, stream>>>(x, encW, encB, encT);
  k_sel<<<dim3(16), 256, 0, stream>>>(x, selW, selB, out + OUT1_F);
  k_wrep<<<dim3(1024), 256, 0, stream>>>(lifW, Wt);
  k_spike<<<dim3(2048), 64, 0, stream>>>(noise, encT, bitsP);
  k_expand8<<<dim3(2048), 64, 0, stream>>>(bitsP, spf);
  k_lif8<<<dim3(32768), 64, 0, stream>>>(Wt, lifB, spf, cb);
  k_reduce<<<dim3(16384), 256, 0, stream>>>(cb, out + OUT1_F, out + OUT2_F);
  k_gemm_relu<<<dim3(8, 64), 256, 0, stream>>>(out + OUT2_F, 1024, W1, 512, b1, hid, 512, 1024);
  k_head2<<<dim3(16), 256, 0, stream>>>(hid, W2, b2, out);
}

// Round 11
// 6381.458 us; speedup vs baseline: 1.5076x; 1.0502x over previous
//
#include <hip/hip_runtime.h>
#include <hip/hip_bf16.h>
#include <stdint.h>
#include <cstdio>
#include <math.h>

// ---------------------------------------------------------------------------
// SpikingTradingAgent on MI355X — round 11.
// Numerics FROZEN (rounds 4-10 passed, absmax 1.07e-2): f32-faithful
// sequential-i einsum chain, f32 membrane update in reference op order,
// -0.0 refractory encoding, CR-exp sigmoid encoder, ballot spike bits.
//
// Round-11: revert to the r8 configuration (u8 spikes + scalar v_fmac hot
// loop — best measured, 6.42 ms) after r9/r10 proved fma_mix is half-rate
// and pk_fma is FLOP-rate-invariant (157 TF spec = 1 scalar fma/SIMD-cycle).
// Two micro-trims, bit-identical: spf relayout [bw][tg][i][lane][8] (per-wave
// i-stride 512B -> imm-offset folding) + unroll 4.
// Ceiling arithmetic: einsum = 5.5e11 f32 FLOP; m07 measured sustained FMA
// rate 103 TF -> k_lif floor 5.34 ms; r8 k_lif ~5.8 ms = 92% of floor.
// ---------------------------------------------------------------------------

typedef unsigned int u32;
typedef unsigned long long u64;

// workspace layout (bytes) — fits the 160MB-confirmed baseline
#define ENCT_OFF 0u                        // f32 [512][4096]              8 MiB
#define BITS_OFF (8u << 20)                // u64 [64][4][512][8]          8 MiB
#define WT_OFF   (16u << 20)               // f32 [512][512][8]            8 MiB
#define SPF_OFF  (24u << 20)               // u8  [64][4][512][64][8]     64 MiB
#define CB_OFF   (88u << 20)               // u32 [4][4096][1024]         64 MiB
#define HID_OFF  (152u << 20)              // f32 [4096][512]              8 MiB
#define WS_NEED  ((size_t)HID_OFF + (8u << 20))

// d_out layout (floats): out0 [4096][3] @0, out1 [4096][4] @12288,
// out2 (mean_spike_rate) [4096][1024] @28672
#define OUT1_F 12288
#define OUT2_F 28672

// ---------------------------------------------------------------------------
// Encoder, f32-faithful: z = x @ enc_W, k-sequential FMA chains, kc=384 panel
// split, + bias, sigmoid via CR expf. Output transposed enc_T[i][b].
// ---------------------------------------------------------------------------
__global__ __launch_bounds__(64) void k_genc(const float* __restrict__ x,
                                             const float* __restrict__ W,
                                             const float* __restrict__ bias,
                                             float* __restrict__ encT) {
  const int lane = threadIdx.x;
  const int bg = blockIdx.x & 63;   // b-group of 64
  const int jg = blockIdx.x >> 6;   // j-group of 8 (64 groups)
  const int b = bg * 64 + lane;
  const int j0 = jg * 8;
  const float* xr = x + (size_t)b * 512;
  float accA[8], accB[8];
#pragma unroll
  for (int u = 0; u < 8; ++u) { accA[u] = 0.0f; accB[u] = 0.0f; }
  for (int k = 0; k < 384; ++k) {
    float xv = xr[k];
#pragma unroll
    for (int u = 0; u < 8; ++u) accA[u] = fmaf(xv, W[k * 512 + j0 + u], accA[u]);
  }
  for (int k = 384; k < 512; ++k) {
    float xv = xr[k];
#pragma unroll
    for (int u = 0; u < 8; ++u) accB[u] = fmaf(xv, W[k * 512 + j0 + u], accB[u]);
  }
#pragma unroll
  for (int u = 0; u < 8; ++u) {
    float z = __fadd_rn(__fadd_rn(accA[u], accB[u]), bias[j0 + u]);
    float ef = (float)exp(-(double)z);          // == correctly-rounded expf
    float enc = 1.0f / (1.0f + ef);
    encT[(size_t)(j0 + u) * 4096 + b] = enc;
  }
}

// ---------------------------------------------------------------------------
// Spike bits -> packed [bw][tg][i][8t]: word (bw,tg,i,tt) bit b =
// (noise[b][t][i] < enc[b][i]) f32, t = tg*8+tt. lane = b -> ballot.
// ---------------------------------------------------------------------------
__global__ __launch_bounds__(64) void k_spike(const float* __restrict__ noise,
                                              const float* __restrict__ encT,
                                              u64* __restrict__ bitsP) {
  const int lane = threadIdx.x;
  const int t = blockIdx.x & 31;
  const int bw = blockIdx.x >> 5;   // 64 b-waves
  const int b = bw * 64 + lane;
  const float* nr = noise + ((size_t)b * 32 + t) * 512;
  u64* dst = bitsP + (((size_t)bw * 4 + (t >> 3)) * 512) * 8 + (t & 7);
  for (int i0 = 0; i0 < 512; i0 += 4) {
    float4 nv = *(const float4*)(nr + i0);
    float e0 = encT[(size_t)(i0 + 0) * 4096 + b];
    float e1 = encT[(size_t)(i0 + 1) * 4096 + b];
    float e2 = encT[(size_t)(i0 + 2) * 4096 + b];
    float e3 = encT[(size_t)(i0 + 3) * 4096 + b];
    u64 m0 = __ballot(nv.x < e0);
    u64 m1 = __ballot(nv.y < e1);
    u64 m2 = __ballot(nv.z < e2);
    u64 m3 = __ballot(nv.w < e3);
    if (lane == 0) {
      dst[(i0 + 0) * 8] = m0; dst[(i0 + 1) * 8] = m1;
      dst[(i0 + 2) * 8] = m2; dst[(i0 + 3) * 8] = m3;
    }
  }
}

// ---------------------------------------------------------------------------
// Expand ballots to per-lane u8 spikes, layout [bw][tg][i][lane][8]:
// per-wave slice is contiguous 512B per i -> imm-offset folding in k_lif.
// ---------------------------------------------------------------------------
__global__ __launch_bounds__(64) void k_expand8(const u64* __restrict__ bitsP,
                                                unsigned char* __restrict__ spf) {
  const int lane = threadIdx.x;
  const int bid = blockIdx.x;       // 2048 = bw(64) x tg(4) x ic(8)
  const int ic = bid & 7;
  const int tg = (bid >> 3) & 3;
  const int bw = bid >> 5;
  const u64* src = bitsP + (((size_t)bw * 4 + tg) * 512) * 8;
  unsigned char* dstb = spf + (((size_t)bw * 4 + tg) * 512) * 512 + lane * 8;
  for (int ii = 0; ii < 64; ++ii) {
    const int i = ic * 64 + ii;
    u64 w = 0;
#pragma unroll
    for (int tt = 0; tt < 8; ++tt) {
      u64 m = src[(size_t)i * 8 + tt];
      w |= ((m >> lane) & 1ULL) << (8 * tt);
    }
    *(u64*)(dstb + (size_t)i * 512) = w;
  }
}

// ---------------------------------------------------------------------------
// W repack: Wt[slab][i][8] = lif_W[p][i][hs*8 .. hs*8+7], slab = p*128+hs
// ---------------------------------------------------------------------------
__global__ __launch_bounds__(256) void k_wrep(const float* __restrict__ lifW,
                                              float* __restrict__ Wt) {
  int idx = blockIdx.x * 256 + threadIdx.x;   // 262144 = 4p x 128hs x 512i
  int i = idx & 511;
  int hs = (idx >> 9) & 127;
  int p = idx >> 16;
  const float* src = lifW + ((size_t)(p * 512 + i)) * 1024 + hs * 8;
  float4 a = *(const float4*)src;
  float4 c = *(const float4*)(src + 4);
  float* dst = Wt + (((size_t)(p * 128 + hs)) * 512 + (size_t)i) * 8;
  *(float4*)dst = a;
  *(float4*)(dst + 4) = c;
}

// ---------------------------------------------------------------------------
// pathway selection: softmax(x @ sel_W + sel_b) -> out1 f32
// ---------------------------------------------------------------------------
__global__ __launch_bounds__(256) void k_sel(const float* __restrict__ x,
                                             const float* __restrict__ selW,
                                             const float* __restrict__ selB,
                                             float* __restrict__ out1) {
  int b = blockIdx.x * 256 + threadIdx.x;
  const float* xr = x + (size_t)b * 512;
  double a0 = 0, a1 = 0, a2 = 0, a3 = 0;
  for (int k = 0; k < 512; ++k) {
    double xv = (double)xr[k];
    float4 w = *(const float4*)(selW + k * 4);
    a0 = fma(xv, (double)w.x, a0);
    a1 = fma(xv, (double)w.y, a1);
    a2 = fma(xv, (double)w.z, a2);
    a3 = fma(xv, (double)w.w, a3);
  }
  a0 += (double)selB[0]; a1 += (double)selB[1];
  a2 += (double)selB[2]; a3 += (double)selB[3];
  double m = fmax(fmax(a0, a1), fmax(a2, a3));
  double e0 = exp(a0 - m), e1 = exp(a1 - m), e2 = exp(a2 - m), e3 = exp(a3 - m);
  double inv = 1.0 / (e0 + e1 + e2 + e3);
  float4 wf = {(float)(e0 * inv), (float)(e1 * inv), (float)(e2 * inv), (float)(e3 * inv)};
  *(float4*)(out1 + (size_t)b * 4) = wf;
}

// ---------------------------------------------------------------------------
// Fused LIF, f32-faithful, 8h x 8t wave tile, lane = b. Pure VMEM hot loop:
// per i: 1 per-lane dwordx2 (8 spike bytes, 512B wave stride -> imm offsets),
// 2 uniform float4 (W row), 8 byte->float cvt, 64 fmaf. acc[tt][h] chains ==
// reference sequential-i f32 chains (spf in {0.0f,1.0f}), bit-identical.
// ---------------------------------------------------------------------------
__global__ __launch_bounds__(64, 4) void k_lif(const float* __restrict__ Wt,
                                               const float* __restrict__ lifB,
                                               const unsigned char* __restrict__ spf,
                                               u32* __restrict__ cb) {
  const int lane = threadIdx.x;
  const int bid = blockIdx.x;          // 32768 = 64 bw x 512 slab
  const int slab = bid & 511;          // p*128 + hs (bw-major: 512 blocks of
  const int bw = bid >> 9;             //  one bw together -> spf slice L2-hot)
  const int p = slab >> 7;
  const int h0 = (slab & 127) * 8;
  const int b0 = bw * 64;
  const float* wbase = Wt + (size_t)slab * 512 * 8;
  const float* biasp = lifB + p * 1024 + h0;

  float mem[8], bias_r[8];
  u32 cbits[8];
#pragma unroll
  for (int h = 0; h < 8; ++h) {
    mem[h] = 0.0f; cbits[h] = 0u;
    bias_r[h] = biasp[h];
  }

#pragma unroll 1
  for (int tg = 0; tg < 4; ++tg) {
    float acc[8][8];
#pragma unroll
    for (int tt = 0; tt < 8; ++tt)
#pragma unroll
      for (int h = 0; h < 8; ++h) acc[tt][h] = 0.0f;

    const unsigned char* sb =
        spf + (((size_t)bw * 4 + tg) * 512) * 512 + lane * 8;

#pragma unroll 4
    for (int i = 0; i < 512; ++i) {
      u64 sv = *(const u64*)(sb + (size_t)i * 512);     // per-lane, coalesced
      float4 w0 = *(const float4*)(wbase + i * 8);      // uniform broadcast
      float4 w1 = *(const float4*)(wbase + i * 8 + 4);
      u32 lo = (u32)sv, hi = (u32)(sv >> 32);
      float sarr[8] = {(float)(lo & 0xffu),        (float)((lo >> 8) & 0xffu),
                       (float)((lo >> 16) & 0xffu), (float)(lo >> 24),
                       (float)(hi & 0xffu),        (float)((hi >> 8) & 0xffu),
                       (float)((hi >> 16) & 0xffu), (float)(hi >> 24)};
#pragma unroll
      for (int tt = 0; tt < 8; ++tt) {
        float sp = sarr[tt];
        acc[tt][0] = fmaf(w0.x, sp, acc[tt][0]);
        acc[tt][1] = fmaf(w0.y, sp, acc[tt][1]);
        acc[tt][2] = fmaf(w0.z, sp, acc[tt][2]);
        acc[tt][3] = fmaf(w0.w, sp, acc[tt][3]);
        acc[tt][4] = fmaf(w1.x, sp, acc[tt][4]);
        acc[tt][5] = fmaf(w1.y, sp, acc[tt][5]);
        acc[tt][6] = fmaf(w1.z, sp, acc[tt][6]);
        acc[tt][7] = fmaf(w1.w, sp, acc[tt][7]);
      }
    }
    // membrane update, reference op order (all f32, no contraction)
#pragma unroll
    for (int tt = 0; tt < 8; ++tt) {
      const int t = tg * 8 + tt;
#pragma unroll
      for (int h = 0; h < 8; ++h) {
        float c = __fadd_rn(acc[tt][h], bias_r[h]);
        float mo = mem[h];
        bool blocked = (__float_as_uint(mo) == 0x80000000u);
        float mn = __fadd_rn(__fmul_rn(mo, 0.9f), c);
        bool sp = (mn >= 1.0f) && (!blocked);
        mem[h] = sp ? -0.0f : mn;
        cbits[h] |= (sp ? 1u : 0u) << t;
      }
    }
  }
  // store: lane owns (b = b0+lane, h = h0..h0+7) -> 8 consecutive u32
  u32* dst = cb + ((size_t)p * 4096 + b0 + lane) * 1024 + h0;
  uint4 v0 = {cbits[0], cbits[1], cbits[2], cbits[3]};
  uint4 v1 = {cbits[4], cbits[5], cbits[6], cbits[7]};
  *(uint4*)dst = v0;
  *(uint4*)(dst + 4) = v1;
}

// ---------------------------------------------------------------------------
// msr[b][h]: faithful f32: per t: s = p-ascending chain; acc = fl(acc+s); /32.
// ---------------------------------------------------------------------------
__global__ __launch_bounds__(256) void k_reduce(const u32* __restrict__ cb,
                                                const float* __restrict__ w,
                                                float* __restrict__ msr) {
  int idx = blockIdx.x * 256 + threadIdx.x;  // 4194304
  int h = idx & 1023;
  int b = idx >> 10;
  float4 wv = *(const float4*)(w + (size_t)b * 4);
  u32 c0 = cb[((size_t)0 * 4096 + b) * 1024 + h];
  u32 c1 = cb[((size_t)1 * 4096 + b) * 1024 + h];
  u32 c2 = cb[((size_t)2 * 4096 + b) * 1024 + h];
  u32 c3 = cb[((size_t)3 * 4096 + b) * 1024 + h];
  float acc = 0.0f;
#pragma unroll
  for (int t = 0; t < 32; ++t) {
    float s = ((c0 >> t) & 1u) ? wv.x : 0.0f;
    s = __fadd_rn(s, ((c1 >> t) & 1u) ? wv.y : 0.0f);
    s = __fadd_rn(s, ((c2 >> t) & 1u) ? wv.z : 0.0f);
    s = __fadd_rn(s, ((c3 >> t) & 1u) ? wv.w : 0.0f);
    acc = __fadd_rn(acc, s);
  }
  msr[(size_t)b * 1024 + h] = acc * 0.03125f;  // /32 exact
}

// ---------------------------------------------------------------------------
// f32 GEMM + relu (head):  out = relu(A[M,K] @ W[K,N] + bias)
// ---------------------------------------------------------------------------
__global__ __launch_bounds__(256) void k_gemm_relu(const float* __restrict__ A, int lda,
                                                   const float* __restrict__ W, int ldw,
                                                   const float* __restrict__ bias,
                                                   float* __restrict__ out, int ldo, int K) {
  __shared__ float As[16][65];
  __shared__ float Bs[16][64];
  const int tid = threadIdx.x;
  const int tx = tid & 15, ty = tid >> 4;
  const int n0 = blockIdx.x * 64, m0 = blockIdx.y * 64;
  const int sm = tid >> 2, skq = tid & 3;
  float acc[4][4] = {};
  for (int k0 = 0; k0 < K; k0 += 16) {
    float4 av = *(const float4*)(A + (size_t)(m0 + sm) * lda + k0 + skq * 4);
    As[skq * 4 + 0][sm] = av.x;
    As[skq * 4 + 1][sm] = av.y;
    As[skq * 4 + 2][sm] = av.z;
    As[skq * 4 + 3][sm] = av.w;
#pragma unroll
    for (int j = 0; j < 4; ++j) {
      int k = j * 4 + (tid >> 6);
      int n = tid & 63;
      Bs[k][n] = W[(size_t)(k0 + k) * ldw + n0 + n];
    }
    __syncthreads();
#pragma unroll
    for (int k = 0; k < 16; ++k) {
      float a[4], bb[4];
#pragma unroll
      for (int i = 0; i < 4; ++i) a[i] = As[k][ty * 4 + i];
#pragma unroll
      for (int i = 0; i < 4; ++i) bb[i] = Bs[k][tx * 4 + i];
#pragma unroll
      for (int i = 0; i < 4; ++i)
#pragma unroll
        for (int ii = 0; ii < 4; ++ii) acc[i][ii] = fmaf(a[i], bb[ii], acc[i][ii]);
    }
    __syncthreads();
  }
#pragma unroll
  for (int i = 0; i < 4; ++i)
#pragma unroll
    for (int ii = 0; ii < 4; ++ii) {
      float v = fmaxf(acc[i][ii] + bias[n0 + tx * 4 + ii], 0.0f);
      out[(size_t)(m0 + ty * 4 + i) * ldo + n0 + tx * 4 + ii] = v;
    }
}

// ---------------------------------------------------------------------------
// out0 = hid @ out_W2 + b2   (one thread per b)
// ---------------------------------------------------------------------------
__global__ __launch_bounds__(256) void k_head2(const float* __restrict__ hid,
                                               const float* __restrict__ W2,
                                               const float* __restrict__ b2,
                                               float* __restrict__ out0) {
  __shared__ float w2s[512][3];
  int tid = threadIdx.x;
  for (int i = tid; i < 1536; i += 256) ((float*)w2s)[i] = W2[i];
  __syncthreads();
  int b = blockIdx.x * 256 + tid;
  const float* hr = hid + (size_t)b * 512;
  float a0 = 0, a1 = 0, a2 = 0;
  for (int j = 0; j < 512; ++j) {
    float h = hr[j];
    a0 = fmaf(h, w2s[j][0], a0);
    a1 = fmaf(h, w2s[j][1], a1);
    a2 = fmaf(h, w2s[j][2], a2);
  }
  out0[b * 3 + 0] = a0 + b2[0];
  out0[b * 3 + 1] = a1 + b2[1];
  out0[b * 3 + 2] = a2 + b2[2];
}

// ---------------------------------------------------------------------------
extern "C" void kernel_launch(void* const* d_in, const int* in_sizes, int n_in,
                              void* d_out, int out_size, void* d_ws, size_t ws_size,
                              hipStream_t stream) {
  const float* x = (const float*)d_in[0];
  const float* noise = (const float*)d_in[1];
  const float* encW = (const float*)d_in[3];
  const float* encB = (const float*)d_in[4];
  const float* selW = (const float*)d_in[5];
  const float* selB = (const float*)d_in[6];
  const float* lifW = (const float*)d_in[7];
  const float* lifB = (const float*)d_in[8];
  const float* W1 = (const float*)d_in[9];
  const float* b1 = (const float*)d_in[10];
  const float* W2 = (const float*)d_in[11];
  const float* b2 = (const float*)d_in[12];
  float* out = (float*)d_out;
  unsigned char* ws = (unsigned char*)d_ws;

  if (ws_size < WS_NEED) {
    fprintf(stderr, "kernel_launch: ws too small (%zu < %zu)\n", ws_size, (size_t)WS_NEED);
    return;
  }

  float* encT = (float*)(ws + ENCT_OFF);
  u64* bitsP = (u64*)(ws + BITS_OFF);
  float* Wt = (float*)(ws + WT_OFF);
  unsigned char* spf = ws + SPF_OFF;
  u32* cb = (u32*)(ws + CB_OFF);
  float* hid = (float*)(ws + HID_OFF);

  // 1. encoder (f32-faithful) -> enc_T
  k_genc<<<dim3(4096), 64, 0, stream>>>(x, encW, encB, encT);
  // 2. pathway weights -> out1 (f32)
  k_sel<<<dim3(16), 256, 0, stream>>>(x, selW, selB, out + OUT1_F);
  // 3. W repack [slab][i][8]
  k_wrep<<<dim3(1024), 256, 0, stream>>>(lifW, Wt);
  // 4. spike bits, f32 compare, ballot -> [bw][tg][i][tt]
  k_spike<<<dim3(2048), 64, 0, stream>>>(noise, encT, bitsP);
  // 5. expand ballots to per-lane spike bytes [bw][tg][i][lane][8]
  k_expand8<<<dim3(2048), 64, 0, stream>>>(bitsP, spf);
  // 6. fused LIF, pure-VMEM pipelined (dominant)
  k_lif<<<dim3(32768), 64, 0, stream>>>(Wt, lifB, spf, cb);
  // 7. mean spike rate (faithful f32 p/t chains) -> out2
  k_reduce<<<dim3(16384), 256, 0, stream>>>(cb, out + OUT1_F, out + OUT2_F);
  // 8. hid = relu(msr @ W1 + b1)
  k_gemm_relu<<<dim3(8, 64), 256, 0, stream>>>(out + OUT2_F, 1024, W1, 512, b1, hid, 512, 1024);
  // 9. out0 = hid @ W2 + b2
  k_head2<<<dim3(16), 256, 0, stream>>>(hid, W2, b2, out);
}